// Round 15
// baseline (270.893 us; speedup 1.0000x reference)
//
#include <hip/hip_runtime.h>
#include <cmath>

// PointTransformerBlock fused pipeline for MI355X (round 15).
// r14 post-mortem: gather plateaued ~79us across 5 MLP/cache variants while
// VALU 21% / HBM 15% / L2 8% — try the untried axis: per-edge instruction
// count. Gather now uses uint2 lanes (2 channels/lane, half-waves h=0/1 take
// 8 edges each -> 16 edges/iter): halves load instrs + serial iters, doubles
// edges in flight. Tail: pre1+pre2 merged (chained GEMMs, A2 never stored);
// hist+scatter edge reads int4-vectorized.
//
// Math (exact algebra):
//   w_j[c] = exp(-(x_j@Wsrc2 + p_j.M5)[c]),  Wsrc2 = W_src@attn_w1@attn_w2
//   v_j[c] = (x_j@W_lin)[c] - p_j.M3[c]
//   out_i[c] = (Sum_j w v)/(Sum_j w) + (bc + p_i.M3)[c], j over in-edges+self
//   then ELU, BatchNorm.  M5 = M3@attn_w1@attn_w2 (chained), M3 = pos_w1@pos_w2.

__device__ __forceinline__ unsigned bf16r(float f) {
    unsigned u = __float_as_uint(f);
    return (u + 0x7fffu + ((u >> 16) & 1u)) >> 16;   // round-to-nearest-even
}
__device__ __forceinline__ float bfhi(unsigned u) { return __uint_as_float(u & 0xffff0000u); }
__device__ __forceinline__ float bflo(unsigned u) { return __uint_as_float(u << 16); }

// ---- 64x64x64 GEMM microkernel: 256 threads, 4x4 outputs/thread ----
__device__ __forceinline__ void gemm_tile(const float (*xs)[68], const float (*Wl)[64],
                                          int tx, int ty, float acc[4][4])
{
    #pragma unroll
    for (int i = 0; i < 4; ++i)
        #pragma unroll
        for (int j = 0; j < 4; ++j) acc[i][j] = 0.f;
    for (int k = 0; k < 64; k += 4) {
        float4 b0 = *(const float4*)&Wl[k + 0][4 * tx];
        float4 b1 = *(const float4*)&Wl[k + 1][4 * tx];
        float4 b2 = *(const float4*)&Wl[k + 2][4 * tx];
        float4 b3 = *(const float4*)&Wl[k + 3][4 * tx];
        #pragma unroll
        for (int i = 0; i < 4; ++i) {
            float4 a = *(const float4*)&xs[4 * ty + i][k];
            acc[i][0] += a.x * b0.x + a.y * b1.x + a.z * b2.x + a.w * b3.x;
            acc[i][1] += a.x * b0.y + a.y * b1.y + a.z * b2.y + a.w * b3.y;
            acc[i][2] += a.x * b0.z + a.y * b1.z + a.z * b2.z + a.w * b3.z;
            acc[i][3] += a.x * b0.w + a.y * b1.w + a.z * b2.w + a.w * b3.w;
        }
    }
}

// ONE precompute kernel.
// block0: Wsrc2 = W_src@(attn_w1@attn_w2), chained in-block (A2 never stored).
// block1: M3 = pos_w1@pos_w2, bc; then M5 = (M3@attn_w1)@attn_w2 chained.
// blocks>=2: zero cnt + stats.
__global__ __launch_bounds__(256) void k_pre(
    const float* __restrict__ W_src,
    const float* __restrict__ pos_w1, const float* __restrict__ pos_b1,
    const float* __restrict__ pos_w2, const float* __restrict__ pos_b2,
    const float* __restrict__ attn_w1, const float* __restrict__ attn_w2,
    float* __restrict__ Wsrc2, float* __restrict__ M3, float* __restrict__ M5,
    float* __restrict__ bc,
    int* __restrict__ cnt, float* __restrict__ stats, int n_nodes)
{
    int t = threadIdx.x;
    if (blockIdx.x == 0) {
        __shared__ __align__(16) float As[64][68];
        __shared__ __align__(16) float Bs[64][64];
        int lk = t & 63, lr = t >> 6;
        for (int i = 0; i < 16; ++i) {
            As[lr + 4 * i][lk] = attn_w1[(lr + 4 * i) * 64 + lk];
            Bs[lr + 4 * i][lk] = attn_w2[(lr + 4 * i) * 64 + lk];
        }
        __syncthreads();
        int tx = t & 15, ty = t >> 4;
        float acc[4][4];
        gemm_tile(As, Bs, tx, ty, acc);     // acc = A2 tile
        __syncthreads();                    // all reads of Bs done
        #pragma unroll
        for (int i = 0; i < 4; ++i)
            #pragma unroll
            for (int j = 0; j < 4; ++j)
                Bs[4 * ty + i][4 * tx + j] = acc[i][j];   // Bs = A2
        for (int i = 0; i < 16; ++i)
            As[lr + 4 * i][lk] = W_src[(lr + 4 * i) * 64 + lk];
        __syncthreads();
        float acc2[4][4];
        gemm_tile(As, Bs, tx, ty, acc2);    // W_src @ A2
        #pragma unroll
        for (int i = 0; i < 4; ++i)
            *(float4*)&Wsrc2[(4 * ty + i) * 64 + 4 * tx] =
                make_float4(acc2[i][0], acc2[i][1], acc2[i][2], acc2[i][3]);
    } else if (blockIdx.x == 1) {
        __shared__ float m3s[192], ts[192];
        int c = t & 63, q = t >> 6;
        if (q < 3) {
            float acc = 0.f;
            for (int h = 0; h < 64; ++h) acc += pos_w1[q * 64 + h] * pos_w2[h * 64 + c];
            m3s[q * 64 + c] = acc;
            M3[q * 64 + c] = acc;
        } else {
            float accb = 0.f;
            for (int h = 0; h < 64; ++h) accb += pos_b1[h] * pos_w2[h * 64 + c];
            bc[c] = accb + pos_b2[c];
        }
        __syncthreads();
        if (q < 3) {
            float acc = 0.f;
            for (int k = 0; k < 64; ++k) acc += m3s[q * 64 + k] * attn_w1[k * 64 + c];
            ts[q * 64 + c] = acc;
        }
        __syncthreads();
        if (q < 3) {
            float acc = 0.f;
            for (int k = 0; k < 64; ++k) acc += ts[q * 64 + k] * attn_w2[k * 64 + c];
            M5[q * 64 + c] = acc;
        }
    } else {
        if (blockIdx.x == 2 && t < 128) stats[t] = 0.f;
        int idx = (blockIdx.x - 2) * 256 + t;
        int stride = (gridDim.x - 2) * 256;
        for (int i = idx; i < n_nodes; i += stride) cnt[i] = 0;
    }
}

// blocks [0,G): pairbf tiles. blocks >= G: edge histogram (int4, overlapped).
// pairbf[n*64+c] = {bf16(exp(-(x@Wsrc2 + p.M5))), bf16(x@Wlin - p.M3)}
__global__ __launch_bounds__(256, 4) void k_gemm_pair_hist(
    const float* __restrict__ x, const float* __restrict__ pos,
    const float* __restrict__ Wsrc2, const float* __restrict__ Wlin,
    const float* __restrict__ M3, const float* __restrict__ M5,
    unsigned* __restrict__ pairbf, int n_nodes,
    const int* __restrict__ ei, int* __restrict__ cnt, int n_edges, int G)
{
    int t = threadIdx.x;
    if ((int)blockIdx.x >= G) {
        int idx = ((int)blockIdx.x - G) * 256 + t;
        int stride = ((int)gridDim.x - G) * 256;
        int n4 = n_edges >> 2;
        const int4* d4 = (const int4*)(ei + n_edges);
        for (int i = idx; i < n4; i += stride) {
            int4 d = d4[i];
            atomicAdd(&cnt[d.x], 1);
            atomicAdd(&cnt[d.y], 1);
            atomicAdd(&cnt[d.z], 1);
            atomicAdd(&cnt[d.w], 1);
        }
        for (int i = (n4 << 2) + idx; i < n_edges; i += stride)
            atomicAdd(&cnt[ei[n_edges + i]], 1);
        return;
    }
    __shared__ __align__(16) float xs[64][68];
    __shared__ __align__(16) float Wl[64][64];
    __shared__ float ps[192];
    __shared__ float m3s[192], m5s[192];
    int tx = t & 15;
    int ty = t >> 4;
    int nbase = blockIdx.x * 64;
    int lk = t & 63;
    int lr = t >> 6;

    for (int i = 0; i < 16; ++i) {
        int n = lr + 4 * i;
        int gn = nbase + n;
        xs[n][lk] = (gn < n_nodes) ? x[gn * 64 + lk] : 0.f;
    }
    if (t < 192) {
        int gi = nbase * 3 + t;
        ps[t] = (gi < n_nodes * 3) ? pos[gi] : 0.f;
        m3s[t] = M3[t];
        m5s[t] = M5[t];
    }
    for (int i = 0; i < 16; ++i) Wl[lr + 4 * i][lk] = Wsrc2[(lr + 4 * i) * 64 + lk];
    __syncthreads();

    float acc_s[4][4];
    gemm_tile(xs, Wl, tx, ty, acc_s);

    __syncthreads();
    for (int i = 0; i < 16; ++i) Wl[lr + 4 * i][lk] = Wlin[(lr + 4 * i) * 64 + lk];
    __syncthreads();

    float acc_x[4][4];
    gemm_tile(xs, Wl, tx, ty, acc_x);

    #pragma unroll
    for (int i = 0; i < 4; ++i) {
        int n = 4 * ty + i;
        int gn = nbase + n;
        if (gn < n_nodes) {
            float px = ps[3 * n], py = ps[3 * n + 1], pz = ps[3 * n + 2];
            int c0 = 4 * tx;
            float g50 = px * m5s[c0]     + py * m5s[64 + c0]     + pz * m5s[128 + c0];
            float g51 = px * m5s[c0 + 1] + py * m5s[64 + c0 + 1] + pz * m5s[128 + c0 + 1];
            float g52 = px * m5s[c0 + 2] + py * m5s[64 + c0 + 2] + pz * m5s[128 + c0 + 2];
            float g53 = px * m5s[c0 + 3] + py * m5s[64 + c0 + 3] + pz * m5s[128 + c0 + 3];
            float g30 = px * m3s[c0]     + py * m3s[64 + c0]     + pz * m3s[128 + c0];
            float g31 = px * m3s[c0 + 1] + py * m3s[64 + c0 + 1] + pz * m3s[128 + c0 + 1];
            float g32 = px * m3s[c0 + 2] + py * m3s[64 + c0 + 2] + pz * m3s[128 + c0 + 2];
            float g33 = px * m3s[c0 + 3] + py * m3s[64 + c0 + 3] + pz * m3s[128 + c0 + 3];
            uint4 w;
            w.x = (bf16r(__expf(-(acc_s[i][0] + g50))) << 16) | bf16r(acc_x[i][0] - g30);
            w.y = (bf16r(__expf(-(acc_s[i][1] + g51))) << 16) | bf16r(acc_x[i][1] - g31);
            w.z = (bf16r(__expf(-(acc_s[i][2] + g52))) << 16) | bf16r(acc_x[i][2] - g32);
            w.w = (bf16r(__expf(-(acc_s[i][3] + g53))) << 16) | bf16r(acc_x[i][3] - g33);
            *(uint4*)&pairbf[gn * 64 + c0] = w;
        }
    }
}

// ---- hierarchical exclusive scan over n counters (chunks of 4096) ----
#define SCAN_CHUNK 4096

__global__ __launch_bounds__(256) void k_scan_partial(const int* __restrict__ cnt,
                                                      int* __restrict__ bsum, int n)
{
    __shared__ int wsh[4];
    int b = blockIdx.x, t = threadIdx.x;
    int base = b * SCAN_CHUNK + t * 16;
    int s = 0;
    #pragma unroll
    for (int i = 0; i < 16; ++i) {
        int idx = base + i;
        if (idx < n) s += cnt[idx];
    }
    for (int off = 32; off; off >>= 1) s += __shfl_down(s, off, 64);
    int lane = t & 63, wv = t >> 6;
    if (lane == 0) wsh[wv] = s;
    __syncthreads();
    if (t == 0) bsum[b] = wsh[0] + wsh[1] + wsh[2] + wsh[3];
}

__global__ __launch_bounds__(256) void k_scan_final(const int* __restrict__ cnt,
                                                    const int* __restrict__ bsum,
                                                    int* __restrict__ rowptr,
                                                    int* __restrict__ cursor,
                                                    int n, int nch, int n_edges)
{
    __shared__ int wsh[4];
    __shared__ int bb;
    int b = blockIdx.x, t = threadIdx.x;
    if (t == 0) {
        int acc = 0;
        for (int c = 0; c < b; ++c) acc += bsum[c];
        bb = acc;
        if (b == nch - 1) rowptr[n] = n_edges;
    }
    int base = b * SCAN_CHUNK + t * 16;
    int v[16];
    int s = 0;
    #pragma unroll
    for (int i = 0; i < 16; ++i) {
        int idx = base + i;
        v[i] = (idx < n) ? cnt[idx] : 0;
        s += v[i];
    }
    int lane = t & 63, wv = t >> 6;
    int inc = s;
    for (int off = 1; off < 64; off <<= 1) {
        int u = __shfl_up(inc, off, 64);
        if (lane >= off) inc += u;
    }
    if (lane == 63) wsh[wv] = inc;
    __syncthreads();
    if (t == 0) {
        int acc = 0;
        for (int w = 0; w < 4; ++w) { int tmp = wsh[w]; wsh[w] = acc; acc += tmp; }
    }
    __syncthreads();
    int run = bb + wsh[wv] + inc - s;   // exclusive start for this thread
    #pragma unroll
    for (int i = 0; i < 16; ++i) {
        int idx = base + i;
        if (idx < n) {
            rowptr[idx] = run;
            cursor[idx] = run;
            run += v[i];
        }
    }
}

// csr_src stores src*32 (uint2-row offset). int4-vectorized edge reads.
__global__ __launch_bounds__(256) void k_scatter(const int* __restrict__ ei,
                                                 int* __restrict__ cursor,
                                                 int* __restrict__ csr_src,
                                                 int n_edges)
{
    int i4 = blockIdx.x * blockDim.x + threadIdx.x;
    int n4 = n_edges >> 2;
    if (i4 < n4) {
        int4 sv = ((const int4*)ei)[i4];
        int4 dv = ((const int4*)(ei + n_edges))[i4];
        int p;
        p = atomicAdd(&cursor[dv.x], 1); csr_src[p] = sv.x * 32;
        p = atomicAdd(&cursor[dv.y], 1); csr_src[p] = sv.y * 32;
        p = atomicAdd(&cursor[dv.z], 1); csr_src[p] = sv.z * 32;
        p = atomicAdd(&cursor[dv.w], 1); csr_src[p] = sv.w * 32;
    } else {
        int e = (n4 << 2) + (i4 - n4);
        if (e < n_edges) {
            int dst = ei[n_edges + e];
            int p = atomicAdd(&cursor[dst], 1);
            csr_src[p] = ei[e] * 32;
        }
    }
}

// uint2 gather: lane s<32 owns channels {2s,2s+1}; half-waves h=0/1 each take
// 8 edges -> 16 edges/iteration. shfl_xor(32) merges halves per node.
__global__ __launch_bounds__(256) void k_gather(
    const int* __restrict__ rowptr, const int* __restrict__ csr_src,
    const uint2* __restrict__ pb2, const float* __restrict__ pos,
    const float* __restrict__ M3, const float* __restrict__ bc,
    float* __restrict__ out, float* __restrict__ stats, int n_nodes)
{
    int t = threadIdx.x;
    int lane = t & 63;
    int s = lane & 31;
    int h = lane >> 5;
    int c0 = 2 * s;
    float bc0 = bc[c0], bc1 = bc[c0 + 1];
    float m30a = M3[c0],     m31a = M3[64 + c0],     m32a = M3[128 + c0];
    float m30b = M3[c0 + 1], m31b = M3[64 + c0 + 1], m32b = M3[128 + c0 + 1];

    int wid = (blockIdx.x * blockDim.x + t) >> 6;
    int nw = (gridDim.x * blockDim.x) >> 6;

    float lsx = 0.f, lqx = 0.f, lsy = 0.f, lqy = 0.f;

    for (int i = wid; i < n_nodes; i += nw) {
        int beg = rowptr[i], end = rowptr[i + 1];
        float zzx = 0.f, zzy = 0.f, SSx = 0.f, SSy = 0.f;
        if (h == 0) {
            uint2 up = pb2[i * 32 + s];       // self loop (half 0 only)
            float w0 = bfhi(up.x), w1 = bfhi(up.y);
            zzx = w0; SSx = w0 * bflo(up.x);
            zzy = w1; SSy = w1 * bflo(up.y);
        }
        int k0 = beg;
        for (; k0 + 16 <= end; k0 += 16) {
            int kk = k0 + h * 8;
            int e0 = csr_src[kk],     e1 = csr_src[kk + 1];
            int e2 = csr_src[kk + 2], e3 = csr_src[kk + 3];
            int e4 = csr_src[kk + 4], e5 = csr_src[kk + 5];
            int e6 = csr_src[kk + 6], e7 = csr_src[kk + 7];
            uint2 u0 = pb2[e0 + s], u1 = pb2[e1 + s];
            uint2 u2 = pb2[e2 + s], u3 = pb2[e3 + s];
            uint2 u4 = pb2[e4 + s], u5 = pb2[e5 + s];
            uint2 u6 = pb2[e6 + s], u7 = pb2[e7 + s];
            float a0 = bfhi(u0.x), a1 = bfhi(u1.x), a2 = bfhi(u2.x), a3 = bfhi(u3.x);
            float a4 = bfhi(u4.x), a5 = bfhi(u5.x), a6 = bfhi(u6.x), a7 = bfhi(u7.x);
            float b0 = bfhi(u0.y), b1 = bfhi(u1.y), b2 = bfhi(u2.y), b3 = bfhi(u3.y);
            float b4 = bfhi(u4.y), b5 = bfhi(u5.y), b6 = bfhi(u6.y), b7 = bfhi(u7.y);
            zzx += ((a0 + a1) + (a2 + a3)) + ((a4 + a5) + (a6 + a7));
            zzy += ((b0 + b1) + (b2 + b3)) + ((b4 + b5) + (b6 + b7));
            SSx += a0 * bflo(u0.x) + a1 * bflo(u1.x) + a2 * bflo(u2.x) + a3 * bflo(u3.x)
                 + a4 * bflo(u4.x) + a5 * bflo(u5.x) + a6 * bflo(u6.x) + a7 * bflo(u7.x);
            SSy += b0 * bflo(u0.y) + b1 * bflo(u1.y) + b2 * bflo(u2.y) + b3 * bflo(u3.y)
                 + b4 * bflo(u4.y) + b5 * bflo(u5.y) + b6 * bflo(u6.y) + b7 * bflo(u7.y);
        }
        int r = end - k0;
        int lo = h * 8;
        int hi = min(r, 8 + lo);
        for (int k = k0 + lo; k < k0 + hi; ++k) {
            uint2 u = pb2[csr_src[k] + s];
            float w0 = bfhi(u.x), w1 = bfhi(u.y);
            zzx += w0; SSx += w0 * bflo(u.x);
            zzy += w1; SSy += w1 * bflo(u.y);
        }
        zzx += __shfl_xor(zzx, 32, 64);
        SSx += __shfl_xor(SSx, 32, 64);
        zzy += __shfl_xor(zzy, 32, 64);
        SSy += __shfl_xor(SSy, 32, 64);
        if (h == 0) {
            float px = pos[3 * i], py = pos[3 * i + 1], pz = pos[3 * i + 2];
            float ddi0 = bc0 + px * m30a + py * m31a + pz * m32a;
            float ddi1 = bc1 + px * m30b + py * m31b + pz * m32b;
            float v0 = SSx / zzx + ddi0;
            float v1 = SSy / zzy + ddi1;
            v0 = (v0 > 0.f) ? v0 : expm1f(v0);
            v1 = (v1 > 0.f) ? v1 : expm1f(v1);
            *(float2*)&out[i * 64 + c0] = make_float2(v0, v1);
            lsx += v0; lqx += v0 * v0;
            lsy += v1; lqy += v1 * v1;
        }
    }

    __shared__ float shx[256], shqx[256], shy[256], shqy[256];
    shx[t] = lsx; shqx[t] = lqx; shy[t] = lsy; shqy[t] = lqy;
    __syncthreads();
    if (t < 32) {
        float ax  = shx[t]  + shx[t + 64]  + shx[t + 128]  + shx[t + 192];
        float aqx = shqx[t] + shqx[t + 64] + shqx[t + 128] + shqx[t + 192];
        float ay  = shy[t]  + shy[t + 64]  + shy[t + 128]  + shy[t + 192];
        float aqy = shqy[t] + shqy[t + 64] + shqy[t + 128] + shqy[t + 192];
        unsafeAtomicAdd(&stats[2 * t], ax);
        unsafeAtomicAdd(&stats[2 * t + 1], ay);
        unsafeAtomicAdd(&stats[64 + 2 * t], aqx);
        unsafeAtomicAdd(&stats[64 + 2 * t + 1], aqy);
    }
}

__global__ __launch_bounds__(256) void k_bn(
    float4* __restrict__ out4, const float* __restrict__ stats,
    const float* __restrict__ gamma, const float* __restrict__ beta,
    int total4, float inv_n)
{
    __shared__ float ssc[64], ssh[64];
    int t = threadIdx.x;
    if (t < 64) {
        float mean = stats[t] * inv_n;
        float var = stats[64 + t] * inv_n - mean * mean;
        float scale = (1.0f / sqrtf(var + 1e-5f)) * gamma[t];
        ssc[t] = scale;
        ssh[t] = beta[t] - mean * scale;
    }
    __syncthreads();
    for (int idx = blockIdx.x * blockDim.x + t; idx < total4;
         idx += gridDim.x * blockDim.x) {
        float4 v = out4[idx];
        int c0 = (idx << 2) & 63;
        v.x = v.x * ssc[c0]     + ssh[c0];
        v.y = v.y * ssc[c0 + 1] + ssh[c0 + 1];
        v.z = v.z * ssc[c0 + 2] + ssh[c0 + 2];
        v.w = v.w * ssc[c0 + 3] + ssh[c0 + 3];
        out4[idx] = v;
    }
}

extern "C" void kernel_launch(void* const* d_in, const int* in_sizes, int n_in,
                              void* d_out, int out_size, void* d_ws, size_t ws_size,
                              hipStream_t stream)
{
    const float* x        = (const float*)d_in[0];
    const float* pos      = (const float*)d_in[1];
    const int*   ei       = (const int*)d_in[2];
    const float* W_lin    = (const float*)d_in[3];
    const float* W_src    = (const float*)d_in[4];
    const float* pos_w1   = (const float*)d_in[6];
    const float* pos_b1   = (const float*)d_in[7];
    const float* pos_w2   = (const float*)d_in[8];
    const float* pos_b2   = (const float*)d_in[9];
    const float* attn_w1  = (const float*)d_in[10];
    const float* attn_w2  = (const float*)d_in[12];
    const float* gamma    = (const float*)d_in[14];
    const float* beta     = (const float*)d_in[15];

    int n_nodes = in_sizes[0] / 64;
    int n_edges = in_sizes[2] / 2;
    int total = n_nodes * 64;
    int nch = (n_nodes + SCAN_CHUNK - 1) / SCAN_CHUNK;

    unsigned* pairbf = (unsigned*)d_ws;              // total u32
    float* Wsrc2 = (float*)(pairbf + total);         // 4096
    float* M3    = Wsrc2 + 4096;                     // 192
    float* M5    = M3 + 192;                         // 192
    float* bc    = M5 + 192;                         // 64
    float* stats = bc + 64;                          // 128
    int*   cnt     = (int*)(stats + 128);
    int*   rowptr  = cnt + n_nodes;
    int*   cursor  = rowptr + n_nodes + 1;
    int*   csr_src = cursor + n_nodes;
    int*   bsum    = csr_src + n_edges;              // nch (<=64)

    int G = (n_nodes + 63) / 64;
    int n4 = n_edges >> 2;

    k_pre<<<18, 256, 0, stream>>>(W_src, pos_w1, pos_b1, pos_w2, pos_b2,
                                  attn_w1, attn_w2, Wsrc2, M3, M5, bc,
                                  cnt, stats, n_nodes);
    k_gemm_pair_hist<<<G + 256, 256, 0, stream>>>(
        x, pos, Wsrc2, W_lin, M3, M5, pairbf, n_nodes, ei, cnt, n_edges, G);
    k_scan_partial<<<nch, 256, 0, stream>>>(cnt, bsum, n_nodes);
    k_scan_final<<<nch, 256, 0, stream>>>(cnt, bsum, rowptr, cursor,
                                          n_nodes, nch, n_edges);
    k_scatter<<<(n4 + 4 + 255) / 256, 256, 0, stream>>>(ei, cursor, csr_src, n_edges);
    k_gather<<<2048, 256, 0, stream>>>(rowptr, csr_src, (const uint2*)pairbf,
                                       pos, M3, bc, (float*)d_out, stats, n_nodes);
    k_bn<<<2048, 256, 0, stream>>>((float4*)d_out, stats, gamma, beta, total / 4,
                                   1.0f / (float)n_nodes);
}

// Round 18
// 198.395 us; speedup vs baseline: 1.3654x; 1.3654x over previous
//
#include <hip/hip_runtime.h>
#include <cmath>

// PointTransformerBlock fused pipeline for MI355X (round 18).
// r17 post-mortem: cooperative k_gather_bn FAILED — absmax 7.03 = max|ref|,
// i.e. d_out all zero: hipLaunchCooperativeKernel errored (unchecked). The
// fused kernel's extra regs/LDS dropped blocks/CU below 8, and 2048 blocks is
// exactly co-residency capacity -> cooperativeLaunchTooLarge, silent no-op.
// Lesson: no capacity-exact cooperative launches. Revert to the proven r14
// pipeline (198.7us) + keep r15's merged k_pre (verified inside r15's passing
// run): 7 dispatches, separate k_bn.
//
// Math (exact algebra):
//   w_j[c] = exp(-(x_j@Wsrc2 + p_j.M5)[c]),  Wsrc2 = W_src@attn_w1@attn_w2
//   v_j[c] = (x_j@W_lin)[c] - p_j.M3[c]
//   out_i[c] = (Sum_j w v)/(Sum_j w) + (bc + p_i.M3)[c], j over in-edges+self
//   then ELU, BatchNorm.  M5 = M3@attn_w1@attn_w2 (chained), M3 = pos_w1@pos_w2.

__device__ __forceinline__ unsigned bf16r(float f) {
    unsigned u = __float_as_uint(f);
    return (u + 0x7fffu + ((u >> 16) & 1u)) >> 16;   // round-to-nearest-even
}
__device__ __forceinline__ float bfhi(unsigned u) { return __uint_as_float(u & 0xffff0000u); }
__device__ __forceinline__ float bflo(unsigned u) { return __uint_as_float(u << 16); }

// ---- 64x64x64 GEMM microkernel: 256 threads, 4x4 outputs/thread ----
__device__ __forceinline__ void gemm_tile(const float (*xs)[68], const float (*Wl)[64],
                                          int tx, int ty, float acc[4][4])
{
    #pragma unroll
    for (int i = 0; i < 4; ++i)
        #pragma unroll
        for (int j = 0; j < 4; ++j) acc[i][j] = 0.f;
    for (int k = 0; k < 64; k += 4) {
        float4 b0 = *(const float4*)&Wl[k + 0][4 * tx];
        float4 b1 = *(const float4*)&Wl[k + 1][4 * tx];
        float4 b2 = *(const float4*)&Wl[k + 2][4 * tx];
        float4 b3 = *(const float4*)&Wl[k + 3][4 * tx];
        #pragma unroll
        for (int i = 0; i < 4; ++i) {
            float4 a = *(const float4*)&xs[4 * ty + i][k];
            acc[i][0] += a.x * b0.x + a.y * b1.x + a.z * b2.x + a.w * b3.x;
            acc[i][1] += a.x * b0.y + a.y * b1.y + a.z * b2.y + a.w * b3.y;
            acc[i][2] += a.x * b0.z + a.y * b1.z + a.z * b2.z + a.w * b3.z;
            acc[i][3] += a.x * b0.w + a.y * b1.w + a.z * b2.w + a.w * b3.w;
        }
    }
}

// ONE precompute kernel.
// block0: Wsrc2 = W_src@(attn_w1@attn_w2), chained in-block (A2 never stored).
// block1: M3 = pos_w1@pos_w2, bc; then M5 = (M3@attn_w1)@attn_w2 chained.
// blocks>=2: zero cnt + stats.
__global__ __launch_bounds__(256) void k_pre(
    const float* __restrict__ W_src,
    const float* __restrict__ pos_w1, const float* __restrict__ pos_b1,
    const float* __restrict__ pos_w2, const float* __restrict__ pos_b2,
    const float* __restrict__ attn_w1, const float* __restrict__ attn_w2,
    float* __restrict__ Wsrc2, float* __restrict__ M3, float* __restrict__ M5,
    float* __restrict__ bc,
    int* __restrict__ cnt, float* __restrict__ stats, int n_nodes)
{
    int t = threadIdx.x;
    if (blockIdx.x == 0) {
        __shared__ __align__(16) float As[64][68];
        __shared__ __align__(16) float Bs[64][64];
        int lk = t & 63, lr = t >> 6;
        for (int i = 0; i < 16; ++i) {
            As[lr + 4 * i][lk] = attn_w1[(lr + 4 * i) * 64 + lk];
            Bs[lr + 4 * i][lk] = attn_w2[(lr + 4 * i) * 64 + lk];
        }
        __syncthreads();
        int tx = t & 15, ty = t >> 4;
        float acc[4][4];
        gemm_tile(As, Bs, tx, ty, acc);     // acc = A2 tile
        __syncthreads();                    // all reads of Bs done
        #pragma unroll
        for (int i = 0; i < 4; ++i)
            #pragma unroll
            for (int j = 0; j < 4; ++j)
                Bs[4 * ty + i][4 * tx + j] = acc[i][j];   // Bs = A2
        for (int i = 0; i < 16; ++i)
            As[lr + 4 * i][lk] = W_src[(lr + 4 * i) * 64 + lk];
        __syncthreads();
        float acc2[4][4];
        gemm_tile(As, Bs, tx, ty, acc2);    // W_src @ A2
        #pragma unroll
        for (int i = 0; i < 4; ++i)
            *(float4*)&Wsrc2[(4 * ty + i) * 64 + 4 * tx] =
                make_float4(acc2[i][0], acc2[i][1], acc2[i][2], acc2[i][3]);
    } else if (blockIdx.x == 1) {
        __shared__ float m3s[192], ts[192];
        int c = t & 63, q = t >> 6;
        if (q < 3) {
            float acc = 0.f;
            for (int h = 0; h < 64; ++h) acc += pos_w1[q * 64 + h] * pos_w2[h * 64 + c];
            m3s[q * 64 + c] = acc;
            M3[q * 64 + c] = acc;
        } else {
            float accb = 0.f;
            for (int h = 0; h < 64; ++h) accb += pos_b1[h] * pos_w2[h * 64 + c];
            bc[c] = accb + pos_b2[c];
        }
        __syncthreads();
        if (q < 3) {
            float acc = 0.f;
            for (int k = 0; k < 64; ++k) acc += m3s[q * 64 + k] * attn_w1[k * 64 + c];
            ts[q * 64 + c] = acc;
        }
        __syncthreads();
        if (q < 3) {
            float acc = 0.f;
            for (int k = 0; k < 64; ++k) acc += ts[q * 64 + k] * attn_w2[k * 64 + c];
            M5[q * 64 + c] = acc;
        }
    } else {
        if (blockIdx.x == 2 && t < 128) stats[t] = 0.f;
        int idx = (blockIdx.x - 2) * 256 + t;
        int stride = (gridDim.x - 2) * 256;
        for (int i = idx; i < n_nodes; i += stride) cnt[i] = 0;
    }
}

// blocks [0,G): pairbf tiles. blocks >= G: edge histogram (overlapped).
// pairbf[n*64+c] = {bf16(exp(-(x@Wsrc2 + p.M5))), bf16(x@Wlin - p.M3)}
__global__ __launch_bounds__(256, 4) void k_gemm_pair_hist(
    const float* __restrict__ x, const float* __restrict__ pos,
    const float* __restrict__ Wsrc2, const float* __restrict__ Wlin,
    const float* __restrict__ M3, const float* __restrict__ M5,
    unsigned* __restrict__ pairbf, int n_nodes,
    const int* __restrict__ ei, int* __restrict__ cnt, int n_edges, int G)
{
    int t = threadIdx.x;
    if ((int)blockIdx.x >= G) {
        int idx = ((int)blockIdx.x - G) * 256 + t;
        int stride = ((int)gridDim.x - G) * 256;
        for (int i = idx; i < n_edges; i += stride)
            atomicAdd(&cnt[ei[n_edges + i]], 1);
        return;
    }
    __shared__ __align__(16) float xs[64][68];
    __shared__ __align__(16) float Wl[64][64];
    __shared__ float ps[192];
    __shared__ float m3s[192], m5s[192];
    int tx = t & 15;
    int ty = t >> 4;
    int nbase = blockIdx.x * 64;
    int lk = t & 63;
    int lr = t >> 6;

    for (int i = 0; i < 16; ++i) {
        int n = lr + 4 * i;
        int gn = nbase + n;
        xs[n][lk] = (gn < n_nodes) ? x[gn * 64 + lk] : 0.f;
    }
    if (t < 192) {
        int gi = nbase * 3 + t;
        ps[t] = (gi < n_nodes * 3) ? pos[gi] : 0.f;
        m3s[t] = M3[t];
        m5s[t] = M5[t];
    }
    for (int i = 0; i < 16; ++i) Wl[lr + 4 * i][lk] = Wsrc2[(lr + 4 * i) * 64 + lk];
    __syncthreads();

    float acc_s[4][4];
    gemm_tile(xs, Wl, tx, ty, acc_s);

    __syncthreads();
    for (int i = 0; i < 16; ++i) Wl[lr + 4 * i][lk] = Wlin[(lr + 4 * i) * 64 + lk];
    __syncthreads();

    float acc_x[4][4];
    gemm_tile(xs, Wl, tx, ty, acc_x);

    #pragma unroll
    for (int i = 0; i < 4; ++i) {
        int n = 4 * ty + i;
        int gn = nbase + n;
        if (gn < n_nodes) {
            float px = ps[3 * n], py = ps[3 * n + 1], pz = ps[3 * n + 2];
            int c0 = 4 * tx;
            float g50 = px * m5s[c0]     + py * m5s[64 + c0]     + pz * m5s[128 + c0];
            float g51 = px * m5s[c0 + 1] + py * m5s[64 + c0 + 1] + pz * m5s[128 + c0 + 1];
            float g52 = px * m5s[c0 + 2] + py * m5s[64 + c0 + 2] + pz * m5s[128 + c0 + 2];
            float g53 = px * m5s[c0 + 3] + py * m5s[64 + c0 + 3] + pz * m5s[128 + c0 + 3];
            float g30 = px * m3s[c0]     + py * m3s[64 + c0]     + pz * m3s[128 + c0];
            float g31 = px * m3s[c0 + 1] + py * m3s[64 + c0 + 1] + pz * m3s[128 + c0 + 1];
            float g32 = px * m3s[c0 + 2] + py * m3s[64 + c0 + 2] + pz * m3s[128 + c0 + 2];
            float g33 = px * m3s[c0 + 3] + py * m3s[64 + c0 + 3] + pz * m3s[128 + c0 + 3];
            uint4 w;
            w.x = (bf16r(__expf(-(acc_s[i][0] + g50))) << 16) | bf16r(acc_x[i][0] - g30);
            w.y = (bf16r(__expf(-(acc_s[i][1] + g51))) << 16) | bf16r(acc_x[i][1] - g31);
            w.z = (bf16r(__expf(-(acc_s[i][2] + g52))) << 16) | bf16r(acc_x[i][2] - g32);
            w.w = (bf16r(__expf(-(acc_s[i][3] + g53))) << 16) | bf16r(acc_x[i][3] - g33);
            *(uint4*)&pairbf[gn * 64 + c0] = w;
        }
    }
}

// ---- hierarchical exclusive scan over n counters (chunks of 4096) ----
#define SCAN_CHUNK 4096

__global__ __launch_bounds__(256) void k_scan_partial(const int* __restrict__ cnt,
                                                      int* __restrict__ bsum, int n)
{
    __shared__ int wsh[4];
    int b = blockIdx.x, t = threadIdx.x;
    int base = b * SCAN_CHUNK + t * 16;
    int s = 0;
    #pragma unroll
    for (int i = 0; i < 16; ++i) {
        int idx = base + i;
        if (idx < n) s += cnt[idx];
    }
    for (int off = 32; off; off >>= 1) s += __shfl_down(s, off, 64);
    int lane = t & 63, wv = t >> 6;
    if (lane == 0) wsh[wv] = s;
    __syncthreads();
    if (t == 0) bsum[b] = wsh[0] + wsh[1] + wsh[2] + wsh[3];
}

__global__ __launch_bounds__(256) void k_scan_final(const int* __restrict__ cnt,
                                                    const int* __restrict__ bsum,
                                                    int* __restrict__ rowptr,
                                                    int* __restrict__ cursor,
                                                    int n, int nch, int n_edges)
{
    __shared__ int wsh[4];
    __shared__ int bb;
    int b = blockIdx.x, t = threadIdx.x;
    if (t == 0) {
        int acc = 0;
        for (int c = 0; c < b; ++c) acc += bsum[c];
        bb = acc;
        if (b == nch - 1) rowptr[n] = n_edges;
    }
    int base = b * SCAN_CHUNK + t * 16;
    int v[16];
    int s = 0;
    #pragma unroll
    for (int i = 0; i < 16; ++i) {
        int idx = base + i;
        v[i] = (idx < n) ? cnt[idx] : 0;
        s += v[i];
    }
    int lane = t & 63, wv = t >> 6;
    int inc = s;
    for (int off = 1; off < 64; off <<= 1) {
        int u = __shfl_up(inc, off, 64);
        if (lane >= off) inc += u;
    }
    if (lane == 63) wsh[wv] = inc;
    __syncthreads();
    if (t == 0) {
        int acc = 0;
        for (int w = 0; w < 4; ++w) { int tmp = wsh[w]; wsh[w] = acc; acc += tmp; }
    }
    __syncthreads();
    int run = bb + wsh[wv] + inc - s;   // exclusive start for this thread
    #pragma unroll
    for (int i = 0; i < 16; ++i) {
        int idx = base + i;
        if (idx < n) {
            rowptr[idx] = run;
            cursor[idx] = run;
            run += v[i];
        }
    }
}

// csr_src stores src*64 (pre-scaled row offset) to save a shift in gather.
__global__ __launch_bounds__(256) void k_scatter(const int* __restrict__ ei,
                                                 int* __restrict__ cursor,
                                                 int* __restrict__ csr_src,
                                                 int n_edges)
{
    int i = blockIdx.x * blockDim.x + threadIdx.x;
    if (i < n_edges) {
        int dst = ei[n_edges + i];
        int p = atomicAdd(&cursor[dst], 1);
        csr_src[p] = ei[i] * 64;
    }
}

// DUAL-NODE gather: each wave interleaves two independent nodes (i, i+nw),
// 4+4 edges per iteration -> two independent latency chains overlap.
__global__ __launch_bounds__(256) void k_gather(
    const int* __restrict__ rowptr, const int* __restrict__ csr_src,
    const unsigned* __restrict__ pairbf, const float* __restrict__ pos,
    const float* __restrict__ M3, const float* __restrict__ bc,
    float* __restrict__ out, float* __restrict__ stats, int n_nodes)
{
    int t = threadIdx.x;
    int c = t & 63;
    float bcc = bc[c];
    float m30 = M3[c], m31 = M3[64 + c], m32 = M3[128 + c];

    int wid = (blockIdx.x * blockDim.x + t) >> 6;
    int nw = (gridDim.x * blockDim.x) >> 6;
    int nw2 = nw * 2;

    float lsum = 0.f, lsq = 0.f;

    for (int i1 = wid; i1 < n_nodes; i1 += nw2) {
        int i2 = i1 + nw;
        bool h2 = (i2 < n_nodes);
        int beg1 = rowptr[i1], end1 = rowptr[i1 + 1];
        int beg2 = 0, end2 = 0;
        if (h2) { beg2 = rowptr[i2]; end2 = rowptr[i2 + 1]; }

        unsigned up1 = pairbf[i1 * 64 + c];
        float ws1 = bfhi(up1);
        float zz1 = ws1, SS1 = ws1 * bflo(up1);
        float zz2 = 0.f, SS2 = 0.f;
        if (h2) {
            unsigned up2 = pairbf[i2 * 64 + c];
            float ws2 = bfhi(up2);
            zz2 = ws2; SS2 = ws2 * bflo(up2);
        }

        int k1 = beg1, k2 = beg2;
        while (k1 + 4 <= end1 && k2 + 4 <= end2) {
            int a0 = csr_src[k1],     a1 = csr_src[k1 + 1];
            int a2 = csr_src[k1 + 2], a3 = csr_src[k1 + 3];
            int b0 = csr_src[k2],     b1 = csr_src[k2 + 1];
            int b2 = csr_src[k2 + 2], b3 = csr_src[k2 + 3];
            unsigned ua0 = pairbf[a0 + c], ua1 = pairbf[a1 + c];
            unsigned ua2 = pairbf[a2 + c], ua3 = pairbf[a3 + c];
            unsigned ub0 = pairbf[b0 + c], ub1 = pairbf[b1 + c];
            unsigned ub2 = pairbf[b2 + c], ub3 = pairbf[b3 + c];
            float wa0 = bfhi(ua0), wa1 = bfhi(ua1), wa2 = bfhi(ua2), wa3 = bfhi(ua3);
            float wb0 = bfhi(ub0), wb1 = bfhi(ub1), wb2 = bfhi(ub2), wb3 = bfhi(ub3);
            zz1 += (wa0 + wa1) + (wa2 + wa3);
            SS1 += wa0 * bflo(ua0) + wa1 * bflo(ua1) + wa2 * bflo(ua2) + wa3 * bflo(ua3);
            zz2 += (wb0 + wb1) + (wb2 + wb3);
            SS2 += wb0 * bflo(ub0) + wb1 * bflo(ub1) + wb2 * bflo(ub2) + wb3 * bflo(ub3);
            k1 += 4; k2 += 4;
        }
        for (; k1 + 4 <= end1; k1 += 4) {
            int a0 = csr_src[k1],     a1 = csr_src[k1 + 1];
            int a2 = csr_src[k1 + 2], a3 = csr_src[k1 + 3];
            unsigned ua0 = pairbf[a0 + c], ua1 = pairbf[a1 + c];
            unsigned ua2 = pairbf[a2 + c], ua3 = pairbf[a3 + c];
            float wa0 = bfhi(ua0), wa1 = bfhi(ua1), wa2 = bfhi(ua2), wa3 = bfhi(ua3);
            zz1 += (wa0 + wa1) + (wa2 + wa3);
            SS1 += wa0 * bflo(ua0) + wa1 * bflo(ua1) + wa2 * bflo(ua2) + wa3 * bflo(ua3);
        }
        for (; k1 < end1; ++k1) {
            unsigned u0 = pairbf[csr_src[k1] + c];
            float w0 = bfhi(u0);
            zz1 += w0;
            SS1 += w0 * bflo(u0);
        }
        for (; k2 + 4 <= end2; k2 += 4) {
            int b0 = csr_src[k2],     b1 = csr_src[k2 + 1];
            int b2 = csr_src[k2 + 2], b3 = csr_src[k2 + 3];
            unsigned ub0 = pairbf[b0 + c], ub1 = pairbf[b1 + c];
            unsigned ub2 = pairbf[b2 + c], ub3 = pairbf[b3 + c];
            float wb0 = bfhi(ub0), wb1 = bfhi(ub1), wb2 = bfhi(ub2), wb3 = bfhi(ub3);
            zz2 += (wb0 + wb1) + (wb2 + wb3);
            SS2 += wb0 * bflo(ub0) + wb1 * bflo(ub1) + wb2 * bflo(ub2) + wb3 * bflo(ub3);
        }
        for (; k2 < end2; ++k2) {
            unsigned u0 = pairbf[csr_src[k2] + c];
            float w0 = bfhi(u0);
            zz2 += w0;
            SS2 += w0 * bflo(u0);
        }

        {
            float px = pos[3 * i1], py = pos[3 * i1 + 1], pz = pos[3 * i1 + 2];
            float ddi = bcc + px * m30 + py * m31 + pz * m32;
            float v = SS1 / zz1 + ddi;
            v = (v > 0.f) ? v : expm1f(v);
            out[i1 * 64 + c] = v;
            lsum += v;
            lsq += v * v;
        }
        if (h2) {
            float px = pos[3 * i2], py = pos[3 * i2 + 1], pz = pos[3 * i2 + 2];
            float ddi = bcc + px * m30 + py * m31 + pz * m32;
            float v = SS2 / zz2 + ddi;
            v = (v > 0.f) ? v : expm1f(v);
            out[i2 * 64 + c] = v;
            lsum += v;
            lsq += v * v;
        }
    }

    __shared__ float sred[256], sred2[256];
    sred[t] = lsum;
    sred2[t] = lsq;
    __syncthreads();
    if (t < 64) {
        float s = sred[t] + sred[t + 64] + sred[t + 128] + sred[t + 192];
        float q = sred2[t] + sred2[t + 64] + sred2[t + 128] + sred2[t + 192];
        unsafeAtomicAdd(&stats[t], s);
        unsafeAtomicAdd(&stats[64 + t], q);
    }
}

__global__ __launch_bounds__(256) void k_bn(
    float4* __restrict__ out4, const float* __restrict__ stats,
    const float* __restrict__ gamma, const float* __restrict__ beta,
    int total4, float inv_n)
{
    __shared__ float ssc[64], ssh[64];
    int t = threadIdx.x;
    if (t < 64) {
        float mean = stats[t] * inv_n;
        float var = stats[64 + t] * inv_n - mean * mean;
        float scale = (1.0f / sqrtf(var + 1e-5f)) * gamma[t];
        ssc[t] = scale;
        ssh[t] = beta[t] - mean * scale;
    }
    __syncthreads();
    for (int idx = blockIdx.x * blockDim.x + t; idx < total4;
         idx += gridDim.x * blockDim.x) {
        float4 v = out4[idx];
        int c0 = (idx << 2) & 63;
        v.x = v.x * ssc[c0]     + ssh[c0];
        v.y = v.y * ssc[c0 + 1] + ssh[c0 + 1];
        v.z = v.z * ssc[c0 + 2] + ssh[c0 + 2];
        v.w = v.w * ssc[c0 + 3] + ssh[c0 + 3];
        out4[idx] = v;
    }
}

extern "C" void kernel_launch(void* const* d_in, const int* in_sizes, int n_in,
                              void* d_out, int out_size, void* d_ws, size_t ws_size,
                              hipStream_t stream)
{
    const float* x        = (const float*)d_in[0];
    const float* pos      = (const float*)d_in[1];
    const int*   ei       = (const int*)d_in[2];
    const float* W_lin    = (const float*)d_in[3];
    const float* W_src    = (const float*)d_in[4];
    const float* pos_w1   = (const float*)d_in[6];
    const float* pos_b1   = (const float*)d_in[7];
    const float* pos_w2   = (const float*)d_in[8];
    const float* pos_b2   = (const float*)d_in[9];
    const float* attn_w1  = (const float*)d_in[10];
    const float* attn_w2  = (const float*)d_in[12];
    const float* gamma    = (const float*)d_in[14];
    const float* beta     = (const float*)d_in[15];

    int n_nodes = in_sizes[0] / 64;
    int n_edges = in_sizes[2] / 2;
    int total = n_nodes * 64;
    int nch = (n_nodes + SCAN_CHUNK - 1) / SCAN_CHUNK;

    unsigned* pairbf = (unsigned*)d_ws;              // total u32
    float* Wsrc2 = (float*)(pairbf + total);         // 4096
    float* M3    = Wsrc2 + 4096;                     // 192
    float* M5    = M3 + 192;                         // 192
    float* bc    = M5 + 192;                         // 64
    float* stats = bc + 64;                          // 128
    int*   cnt     = (int*)(stats + 128);
    int*   rowptr  = cnt + n_nodes;
    int*   cursor  = rowptr + n_nodes + 1;
    int*   csr_src = cursor + n_nodes;
    int*   bsum    = csr_src + n_edges;              // nch (<=64)

    int G = (n_nodes + 63) / 64;

    k_pre<<<18, 256, 0, stream>>>(W_src, pos_w1, pos_b1, pos_w2, pos_b2,
                                  attn_w1, attn_w2, Wsrc2, M3, M5, bc,
                                  cnt, stats, n_nodes);
    k_gemm_pair_hist<<<G + 512, 256, 0, stream>>>(
        x, pos, Wsrc2, W_lin, M3, M5, pairbf, n_nodes, ei, cnt, n_edges, G);
    k_scan_partial<<<nch, 256, 0, stream>>>(cnt, bsum, n_nodes);
    k_scan_final<<<nch, 256, 0, stream>>>(cnt, bsum, rowptr, cursor,
                                          n_nodes, nch, n_edges);
    k_scatter<<<(n_edges + 255) / 256, 256, 0, stream>>>(ei, cursor, csr_src, n_edges);
    k_gather<<<2048, 256, 0, stream>>>(rowptr, csr_src, pairbf, pos, M3, bc,
                                       (float*)d_out, stats, n_nodes);
    k_bn<<<2048, 256, 0, stream>>>((float4*)d_out, stats, gamma, beta, total / 4,
                                   1.0f / (float)n_nodes);
}